// Round 3
// baseline (514.699 us; speedup 1.0000x reference)
//
#include <hip/hip_runtime.h>

typedef unsigned short u16;
typedef float  f32x4 __attribute__((ext_vector_type(4)));
typedef short  s16x8 __attribute__((ext_vector_type(8)));
typedef unsigned short u16x4 __attribute__((ext_vector_type(4)));

#define NT 4194304   // 16384*256 token-matrix elements

__device__ __forceinline__ u16 f2b(float f) {
    unsigned b = __float_as_uint(f);
    return (u16)((b + 0x7FFFu + ((b >> 16) & 1u)) >> 16);   // RNE
}
__device__ __forceinline__ float b2f(u16 u) { return __uint_as_float(((unsigned)u) << 16); }

// pi(r): bit permutation so swapped-QK^T D-layout == PV A-layout (no shuffles).
__device__ __forceinline__ int perm64(int r) {
    return (r & 0x23) | (((r >> 2) & 3) << 3) | (((r >> 4) & 1) << 2);
}

// async global -> LDS, 16B per lane (HW dest: wave-uniform base + lane*16)
__device__ __forceinline__ void gload16(const u16* g, u16* l) {
    __builtin_amdgcn_global_load_lds(
        (const __attribute__((address_space(1))) unsigned int*)g,
        (__attribute__((address_space(3))) unsigned int*)l,
        16, 0, 0);
}

// ---------------- convert 4 weight matrices fp32 -> bf16, one launch ----------------
__global__ __launch_bounds__(256) void cvt_w4(const float* __restrict__ w0, const float* __restrict__ w1,
                                              const float* __restrict__ w2, const float* __restrict__ w3,
                                              u16* __restrict__ dst) {
    const int z = blockIdx.y;
    const float* src = z == 0 ? w0 : z == 1 ? w1 : z == 2 ? w2 : w3;
    int i = (blockIdx.x * 256 + threadIdx.x) * 4;
    f32x4 v = *(const f32x4*)(src + i);
    u16x4 o;
    o[0] = f2b(v[0]); o[1] = f2b(v[1]); o[2] = f2b(v[2]); o[3] = f2b(v[3]);
    *(u16x4*)(dst + (size_t)z * 65536 + i) = o;
}

// ---------------- fused QKV GEMM: z selects {q,k,v}; A read from fp32 x ----------------
__global__ __launch_bounds__(256) void gemm_qkv(const float* __restrict__ x, const u16* __restrict__ wqkv,
                                                const float* __restrict__ bq, const float* __restrict__ bk,
                                                const float* __restrict__ bv,
                                                u16* __restrict__ q, u16* __restrict__ k, u16* __restrict__ vt,
                                                float qscale) {
    const int tid = threadIdx.x;
    const int wid = tid >> 6, lane = tid & 63, g = lane >> 4, lq = lane & 15;
    const int m0 = blockIdx.x * 64, n0 = blockIdx.y * 64, z = blockIdx.z;
    const u16* W = wqkv + (size_t)z * 65536;
    const float* bias = z == 0 ? bq : z == 1 ? bk : bv;
    const float scale = z == 0 ? qscale : 1.0f;

    // A fragments straight from fp32 x (pack to bf16 once)
    const float* arow = x + (size_t)(m0 + wid * 16 + lq) * 256;
    s16x8 af[8];
#pragma unroll
    for (int kk = 0; kk < 8; ++kk) {
        f32x4 lo = *(const f32x4*)(arow + kk * 32 + g * 8);
        f32x4 hi = *(const f32x4*)(arow + kk * 32 + g * 8 + 4);
        union { s16x8 v; u16 u[8]; } pu;
#pragma unroll
        for (int e = 0; e < 4; ++e) { pu.u[e] = f2b(lo[e]); pu.u[4 + e] = f2b(hi[e]); }
        af[kk] = pu.v;
    }

    f32x4 acc[4];
#pragma unroll
    for (int nf = 0; nf < 4; ++nf) { acc[nf][0]=0.f; acc[nf][1]=0.f; acc[nf][2]=0.f; acc[nf][3]=0.f; }
#pragma unroll
    for (int kk = 0; kk < 8; ++kk) {
#pragma unroll
        for (int nf = 0; nf < 4; ++nf) {
            s16x8 b = *(const s16x8*)(W + (size_t)(n0 + nf * 16 + lq) * 256 + kk * 32 + g * 8);
            acc[nf] = __builtin_amdgcn_mfma_f32_16x16x32_bf16(af[kk], b, acc[nf], 0, 0, 0);
        }
    }

    __shared__ __align__(16) u16 c_lds[64 * 64];
#pragma unroll
    for (int nf = 0; nf < 4; ++nf) {
        float bb = bias[n0 + nf * 16 + lq];
#pragma unroll
        for (int j = 0; j < 4; ++j) {
            float v = (acc[nf][j] + bb) * scale;
            if (z != 2) c_lds[(wid * 16 + (g << 2) + j) * 64 + nf * 16 + lq] = f2b(v);
            else        c_lds[(nf * 16 + lq) * 64 + wid * 16 + (g << 2) + j] = f2b(v);
        }
    }
    __syncthreads();
    if (z != 2) {
        u16* Cd = z == 0 ? q : k;
#pragma unroll
        for (int r = 0; r < 2; ++r) {
            int o = (r * 256 + tid) * 8, row = o >> 6, col = o & 63;
            *(s16x8*)(Cd + (size_t)(m0 + row) * 256 + n0 + col) = *(const s16x8*)(c_lds + row * 64 + col);
        }
    } else {
        int bidx = m0 >> 12, s0 = m0 & 4095;
#pragma unroll
        for (int r = 0; r < 2; ++r) {
            int o = (r * 256 + tid) * 8, drow = o >> 6, col = o & 63;
            *(s16x8*)(vt + (size_t)bidx * 1048576 + (size_t)(n0 + drow) * 4096 + s0 + col) =
                *(const s16x8*)(c_lds + drow * 64 + col);
        }
    }
}

// ---------------- GEMM: C[m][n] = A[m][:] . W[n][:] + bias[n], K=256 (bf16 A) ----------------
template<int RELU>
__global__ __launch_bounds__(256) void gemm_k256(const u16* __restrict__ A, const u16* __restrict__ W,
                                                 const float* __restrict__ bias, u16* __restrict__ Cd) {
    const int tid = threadIdx.x;
    const int wid = tid >> 6, lane = tid & 63, g = lane >> 4, lq = lane & 15;
    const int m0 = blockIdx.x * 64, n0 = blockIdx.y * 64;

    const u16* arow = A + (size_t)(m0 + wid * 16 + lq) * 256;
    f32x4 acc[4];
#pragma unroll
    for (int nf = 0; nf < 4; ++nf) { acc[nf][0]=0.f; acc[nf][1]=0.f; acc[nf][2]=0.f; acc[nf][3]=0.f; }
#pragma unroll
    for (int kk = 0; kk < 8; ++kk) {
        s16x8 a = *(const s16x8*)(arow + kk * 32 + g * 8);
#pragma unroll
        for (int nf = 0; nf < 4; ++nf) {
            s16x8 b = *(const s16x8*)(W + (size_t)(n0 + nf * 16 + lq) * 256 + kk * 32 + g * 8);
            acc[nf] = __builtin_amdgcn_mfma_f32_16x16x32_bf16(a, b, acc[nf], 0, 0, 0);
        }
    }
    __shared__ __align__(16) u16 c_lds[64 * 64];
#pragma unroll
    for (int nf = 0; nf < 4; ++nf) {
        float bb = bias[n0 + nf * 16 + lq];
#pragma unroll
        for (int j = 0; j < 4; ++j) {
            float v = acc[nf][j] + bb;
            if (RELU) v = fmaxf(v, 0.f);
            c_lds[(wid * 16 + (g << 2) + j) * 64 + nf * 16 + lq] = f2b(v);
        }
    }
    __syncthreads();
#pragma unroll
    for (int r = 0; r < 2; ++r) {
        int o = (r * 256 + tid) * 8, row = o >> 6, col = o & 63;
        *(s16x8*)(Cd + (size_t)(m0 + row) * 256 + n0 + col) = *(const s16x8*)(c_lds + row * 64 + col);
    }
}

// ---------------- flash attention v3: 8 waves, QBLK=256, 2 waves/SIMD ----------------
// Q,K: [4][4096][256] bf16 (q pre-scaled by log2e/16). VT: [4][256][4096] bf16.
// Opart: [S][16384][256] bf16 normalized partials. ml: [S][2][16384] f32.
__global__ __launch_bounds__(512, 2) void flash3(const u16* __restrict__ Q, const u16* __restrict__ K,
                                                 const u16* __restrict__ VT, u16* __restrict__ Opart,
                                                 float* __restrict__ ml, int ntiles) {
    __shared__ __align__(16) u16 smem[65536];   // 128KB: 2 x (K 32KB + V 32KB)
    const int tid = threadIdx.x;
    const int wid = tid >> 6, lane = tid & 63, g = lane >> 4, lqi = lane & 15;
    const int b = blockIdx.x >> 4, q0 = (blockIdx.x & 15) << 8;   // 256 q-rows / block
    const int s = blockIdx.y, kvbase = s * (ntiles << 6);

    const u16* kb_ = K + (size_t)b * 4096 * 256;
    const u16* vb_ = VT + (size_t)b * 256 * 4096;

    // Q fragments: rows q0 + wid*32 + qh*16 + lqi
    s16x8 qf[2][8];
#pragma unroll
    for (int qh = 0; qh < 2; ++qh) {
        const u16* qrow = Q + (size_t)(b * 4096 + q0 + wid * 32 + qh * 16 + lqi) * 256;
#pragma unroll
        for (int kk = 0; kk < 8; ++kk) qf[qh][kk] = *(const s16x8*)(qrow + kk * 32 + g * 8);
    }

    // staging source offsets (u16 units); 512 threads cover a 64x256 tile in 4 rounds
    int koff[4], voff[4];
#pragma unroll
    for (int r = 0; r < 4; ++r) {
        int c = r * 512 + tid;
        int row = c >> 5, ch = c & 31;                     // K tile [64][256]: 32 chunks/row
        koff[r] = perm64(row) * 256 + ((ch ^ (row & 7)) << 3);
        int vrow = c >> 3, vch = c & 7;                    // V tile [256][64]: 8 chunks/row
        voff[r] = vrow * 4096 + ((vch ^ (vrow & 7)) << 3);
    }

    f32x4 acc[2][16];
#pragma unroll
    for (int qh = 0; qh < 2; ++qh)
#pragma unroll
        for (int nf = 0; nf < 16; ++nf) { acc[qh][nf][0]=0.f; acc[qh][nf][1]=0.f; acc[qh][nf][2]=0.f; acc[qh][nf][3]=0.f; }
    float mrun[2] = {-1e30f, -1e30f}, lrun[2] = {0.f, 0.f};

    auto STAGE = [&](int bufsel, int t) {
        const u16* kt = kb_ + (size_t)(kvbase + (t << 6)) * 256;
        const u16* vt = vb_ + (kvbase + (t << 6));
        u16* kl = smem + bufsel * 32768;
        u16* vl = kl + 16384;
#pragma unroll
        for (int r = 0; r < 4; ++r) gload16(kt + koff[r], kl + (r * 512 + tid) * 8);
#pragma unroll
        for (int r = 0; r < 4; ++r) gload16(vt + voff[r], vl + (r * 512 + tid) * 8);
    };

    auto COMPUTE = [&](int bufsel) {
        const u16* kbuf = smem + bufsel * 32768;
        const u16* vbuf = kbuf + 16384;
        // ST = K . Q^T
        f32x4 st[2][4];
#pragma unroll
        for (int qh = 0; qh < 2; ++qh)
#pragma unroll
            for (int f = 0; f < 4; ++f) { st[qh][f][0]=0.f; st[qh][f][1]=0.f; st[qh][f][2]=0.f; st[qh][f][3]=0.f; }
        __builtin_amdgcn_s_setprio(1);
#pragma unroll
        for (int kk = 0; kk < 8; ++kk) {
#pragma unroll
            for (int f = 0; f < 4; ++f) {
                int row = f * 16 + lqi;
                s16x8 a = *(const s16x8*)(kbuf + ((row << 5) + (((kk << 2) + g) ^ (row & 7))) * 8);
                st[0][f] = __builtin_amdgcn_mfma_f32_16x16x32_bf16(a, qf[0][kk], st[0][f], 0, 0, 0);
                st[1][f] = __builtin_amdgcn_mfma_f32_16x16x32_bf16(a, qf[1][kk], st[1][f], 0, 0, 0);
            }
        }
        __builtin_amdgcn_s_setprio(0);
        // online softmax (base-2), defer-max rescale
        s16x8 pa[2][2];
#pragma unroll
        for (int qh = 0; qh < 2; ++qh) {
            float rm = -1e30f;
#pragma unroll
            for (int f = 0; f < 4; ++f)
                rm = fmaxf(rm, fmaxf(fmaxf(st[qh][f][0], st[qh][f][1]), fmaxf(st[qh][f][2], st[qh][f][3])));
            rm = fmaxf(rm, __shfl_xor(rm, 16));
            rm = fmaxf(rm, __shfl_xor(rm, 32));
            if (!__all(rm - mrun[qh] <= 8.f)) {
                float mnew = fmaxf(mrun[qh], rm);
                float alpha = exp2f(mrun[qh] - mnew);
#pragma unroll
                for (int j = 0; j < 4; ++j) {
                    float a4 = __shfl(alpha, (g << 2) + j);
#pragma unroll
                    for (int nf = 0; nf < 16; ++nf) acc[qh][nf][j] *= a4;
                }
                mrun[qh] = mnew;
                lrun[qh] *= alpha;
            }
            float ps = 0.f;
#pragma unroll
            for (int f = 0; f < 4; ++f)
#pragma unroll
                for (int j = 0; j < 4; ++j) { float e = exp2f(st[qh][f][j] - mrun[qh]); st[qh][f][j] = e; ps += e; }
            ps += __shfl_xor(ps, 16);
            ps += __shfl_xor(ps, 32);
            lrun[qh] += ps;
#pragma unroll
            for (int kk2 = 0; kk2 < 2; ++kk2) {
                union { s16x8 v; u16 u[8]; } pu;
#pragma unroll
                for (int j2 = 0; j2 < 4; ++j2) { pu.u[j2] = f2b(st[qh][2*kk2][j2]); pu.u[4+j2] = f2b(st[qh][2*kk2+1][j2]); }
                pa[qh][kk2] = pu.v;
            }
        }
        // PV
        __builtin_amdgcn_s_setprio(1);
#pragma unroll
        for (int kk2 = 0; kk2 < 2; ++kk2) {
#pragma unroll
            for (int nf = 0; nf < 16; ++nf) {
                int row = (nf << 4) + lqi;
                s16x8 bv = *(const s16x8*)(vbuf + ((row << 3) + (((kk2 << 2) + g) ^ (row & 7))) * 8);
                acc[0][nf] = __builtin_amdgcn_mfma_f32_16x16x32_bf16(pa[0][kk2], bv, acc[0][nf], 0, 0, 0);
                acc[1][nf] = __builtin_amdgcn_mfma_f32_16x16x32_bf16(pa[1][kk2], bv, acc[1][nf], 0, 0, 0);
            }
        }
        __builtin_amdgcn_s_setprio(0);
    };

    STAGE(0, 0);
    for (int t2 = 0; t2 < ntiles; t2 += 2) {
        __syncthreads();                 // drains stage loads (vmcnt) + prior LDS reads
        STAGE(1, t2 + 1);
        COMPUTE(0);
        __syncthreads();
        if (t2 + 2 < ntiles) STAGE(0, t2 + 2);
        COMPUTE(1);
    }

    // epilogue: normalize, pack to LDS, coalesced store
    __syncthreads();
    float linv[2][4];
#pragma unroll
    for (int qh = 0; qh < 2; ++qh)
#pragma unroll
        for (int j = 0; j < 4; ++j) linv[qh][j] = 1.0f / __shfl(lrun[qh], (g << 2) + j);
    u16* o_lds = smem;   // [256][256] bf16 = 128KB
#pragma unroll
    for (int qh = 0; qh < 2; ++qh)
#pragma unroll
        for (int nf = 0; nf < 16; ++nf)
#pragma unroll
            for (int j = 0; j < 4; ++j)
                o_lds[(wid * 32 + qh * 16 + (g << 2) + j) * 256 + (nf << 4) + lqi] = f2b(acc[qh][nf][j] * linv[qh][j]);
    __syncthreads();
    u16* orow = Opart + (size_t)s * NT + (size_t)(b * 4096 + q0) * 256;
#pragma unroll
    for (int r = 0; r < 16; ++r) {
        int o = (r * 512 + tid) * 8, row = o >> 8, col = o & 255;
        *(s16x8*)(orow + (size_t)row * 256 + col) = *(const s16x8*)(o_lds + row * 256 + col);
    }
    if (lane < 16) {
#pragma unroll
        for (int qh = 0; qh < 2; ++qh) {
            int grow = b * 4096 + q0 + wid * 32 + qh * 16 + lqi;
            ml[s * 32768 + grow]         = mrun[qh];
            ml[s * 32768 + 16384 + grow] = lrun[qh];
        }
    }
}

// ---------------- recombine S kv-split partials ----------------
template<int S>
__global__ __launch_bounds__(256) void recomb_k(const u16* __restrict__ Opart, const float* __restrict__ ml,
                                                u16* __restrict__ out) {
    const int row = blockIdx.x * 4 + (threadIdx.x >> 6);
    const int lane = threadIdx.x & 63;
    float m[S], l[S];
#pragma unroll
    for (int s = 0; s < S; ++s) { m[s] = ml[s * 32768 + row]; l[s] = ml[s * 32768 + 16384 + row]; }
    float mm = m[0];
#pragma unroll
    for (int s = 1; s < S; ++s) mm = fmaxf(mm, m[s]);
    float a[S], tot = 0.f;
#pragma unroll
    for (int s = 0; s < S; ++s) { a[s] = l[s] * exp2f(m[s] - mm); tot += a[s]; }
    float rs = 1.0f / tot;
    float r0 = 0.f, r1 = 0.f, r2 = 0.f, r3 = 0.f;
#pragma unroll
    for (int s = 0; s < S; ++s) {
        float w = a[s] * rs;
        u16x4 v = *(const u16x4*)(Opart + (size_t)s * NT + (size_t)row * 256 + lane * 4);
        r0 += w * b2f(v[0]); r1 += w * b2f(v[1]); r2 += w * b2f(v[2]); r3 += w * b2f(v[3]);
    }
    u16x4 o; o[0] = f2b(r0); o[1] = f2b(r1); o[2] = f2b(r2); o[3] = f2b(r3);
    *(u16x4*)(out + (size_t)row * 256 + lane * 4) = o;
}

// ---------------- LayerNorm(x + add) * g + b ----------------
template<int OUTF32>
__global__ __launch_bounds__(256) void ln_k(const float* __restrict__ x, const u16* __restrict__ add,
                                            const float* __restrict__ gam, const float* __restrict__ bet,
                                            float* __restrict__ outf, u16* __restrict__ outb) {
    const int row = blockIdx.x * 4 + (threadIdx.x >> 6);
    const int lane = threadIdx.x & 63;
    f32x4 xv = *(const f32x4*)(x + (size_t)row * 256 + lane * 4);
    u16x4 av = *(const u16x4*)(add + (size_t)row * 256 + lane * 4);
    float s[4];
#pragma unroll
    for (int i = 0; i < 4; ++i) s[i] = xv[i] + b2f(av[i]);
    float sum = s[0] + s[1] + s[2] + s[3];
    float sq = s[0]*s[0] + s[1]*s[1] + s[2]*s[2] + s[3]*s[3];
#pragma unroll
    for (int d = 1; d < 64; d <<= 1) { sum += __shfl_xor(sum, d); sq += __shfl_xor(sq, d); }
    float mean = sum * (1.f / 256.f);
    float var = sq * (1.f / 256.f) - mean * mean;
    float rstd = rsqrtf(var + 1e-5f);
    f32x4 gv = *(const f32x4*)(gam + lane * 4);
    f32x4 bv = *(const f32x4*)(bet + lane * 4);
    if (OUTF32) {
        f32x4 y;
#pragma unroll
        for (int i = 0; i < 4; ++i) y[i] = (s[i] - mean) * rstd * gv[i] + bv[i];
        *(f32x4*)(outf + (size_t)row * 256 + lane * 4) = y;
    } else {
        u16x4 y;
#pragma unroll
        for (int i = 0; i < 4; ++i) y[i] = f2b((s[i] - mean) * rstd * gv[i] + bv[i]);
        *(u16x4*)(outb + (size_t)row * 256 + lane * 4) = y;
    }
}

extern "C" void kernel_launch(void* const* d_in, const int* in_sizes, int n_in,
                              void* d_out, int out_size, void* d_ws, size_t ws_size,
                              hipStream_t stream) {
    const float* x   = (const float*)d_in[0];
    const float* Wq  = (const float*)d_in[1];
    const float* bq  = (const float*)d_in[2];
    const float* Wk  = (const float*)d_in[3];
    const float* bk  = (const float*)d_in[4];
    const float* Wv  = (const float*)d_in[5];
    const float* bv  = (const float*)d_in[6];
    const float* Wl  = (const float*)d_in[7];
    const float* bl  = (const float*)d_in[8];
    const float* g1  = (const float*)d_in[9];
    const float* be1 = (const float*)d_in[10];
    const float* g2  = (const float*)d_in[11];
    const float* be2 = (const float*)d_in[12];
    float* out = (float*)d_out;

    // buffer map (u16 units):
    // qb [1NT] q -> attn-out ; kb [1NT] k -> h ; vtb [1NT] vT -> h1 ;
    // op [S*NT] partials -> op0 reused as h2 ; wqkv+wl [4*65536] ; ml [S*2*16384] f32
    u16* qb   = (u16*)d_ws;
    u16* kb   = qb + NT;
    u16* vtb  = kb + NT;
    u16* op   = vtb + NT;

    const size_t need4 = ((size_t)7 * NT + 4 * 65536) * 2 + 4 * 32768 * 4;
    const int SPLITS = (ws_size >= need4) ? 4 : 2;

    u16* wqkv = op + (size_t)SPLITS * NT;     // wq, wk, wv contiguous
    u16* wlb  = wqkv + 3 * 65536;
    float* ml = (float*)(wlb + 65536);

    cvt_w4<<<dim3(64, 4), 256, 0, stream>>>(Wq, Wk, Wv, Wl, wqkv);

    // q scaled by (1/sqrt(256)) * log2(e): softmax in base-2 domain
    gemm_qkv<<<dim3(256, 4, 3), 256, 0, stream>>>(x, wqkv, bq, bk, bv, qb, kb, vtb,
                                                  0.0625f * 1.44269504f);

    const int ntiles = 4096 / (64 * SPLITS);
    flash3<<<dim3(64, SPLITS), 512, 0, stream>>>(qb, kb, vtb, op, ml, ntiles);

    if (SPLITS == 4) recomb_k<4><<<4096, 256, 0, stream>>>(op, ml, qb);
    else             recomb_k<2><<<4096, 256, 0, stream>>>(op, ml, qb);

    ln_k<0><<<4096, 256, 0, stream>>>(x, qb, g1, be1, nullptr, kb /* h */);

    dim3 ggrid(256, 4);
    gemm_k256<1><<<ggrid, 256, 0, stream>>>(kb, wlb, bl, vtb /* h1 */);
    gemm_k256<0><<<ggrid, 256, 0, stream>>>(vtb, wlb, bl, op /* h2 */);

    ln_k<1><<<4096, 256, 0, stream>>>(x, op, g2, be2, out, nullptr);
}